// Round 16
// baseline (230.046 us; speedup 1.0000x reference)
//
#include <hip/hip_runtime.h>
#include <math.h>

typedef __attribute__((ext_vector_type(4)))  float f32x4;
typedef __attribute__((ext_vector_type(16))) float f32x16;
typedef __attribute__((ext_vector_type(8)))  short bf16x8;

#define NB   64
#define CD   128
#define TD   2048
#define QBLK 256             // per block (4 waves x 64 rows, dual 32-col tiles)
#define KVB  32
#define NKV  (TD / KVB)      // 64
#define NQT  (TD / QBLK)     // 8

#define TILE_B   8192        // K tile: [cblk 0..15][s 0..31] 16B ; V tile: [sblk 0..3][c 0..127] 16B
#define VBASE    ((size_t)NB * NKV * TILE_B)   // 33,554,432 (total ws = 64 MB)

__device__ __forceinline__ short f2bf(float f) {
    union { float f; unsigned u; } x; x.f = f;
    unsigned r = x.u + 0x7FFFu + ((x.u >> 16) & 1u);   // RNE
    return (short)(r >> 16);
}

__device__ __forceinline__ float ex2(float x) {      // raw v_exp_f32 (1 instr)
    return __builtin_amdgcn_exp2f(x);
}
__device__ __forceinline__ float mx3(float a, float b, float c) {
    return fmaxf(fmaxf(a, b), c);                    // fuses to v_max3_f32
}

__device__ __forceinline__ void gl_lds16(const void* g, void* l) {
    __builtin_amdgcn_global_load_lds(
        (__attribute__((address_space(1))) void*)g,
        (__attribute__((address_space(3))) void*)l, 16, 0, 0);
}

// ---------------------------------------------------------------------------
// Prepass: K -> plane-major transposed tiles [cblk][s][8c], V -> plane-major
// natural tiles [sblk][c][8s]. MFMA b128 reads then need no XOR swizzle.
// ---------------------------------------------------------------------------
__global__ __launch_bounds__(256)
void prepass(const float* __restrict__ qkv, char* __restrict__ ws)
{
    int blk  = blockIdx.x;            // 64 b * 64 (kind,sb)
    int b    = blk >> 6;
    int rem  = blk & 63;
    int kind = rem >> 5;              // 0=K, 1=V
    int sb   = rem & 31;              // 64-row source slab -> 2 tiles
    int s0   = sb * 64;
    int tid  = threadIdx.x;
    const float* src = qkv + ((size_t)b * 3 + 1 + kind) * CD * TD;

    if (kind == 0) {
        // K transpose: stage [s'][c] in LDS, emit plane-major tiles
        __shared__ short Tl[64][CD + 8];
        int su = (tid & 15) * 4;
        int cb = 4 * (tid >> 4);
        #pragma unroll
        for (int it = 0; it < 2; ++it) {
            int c0 = cb + 64 * it;
            f32x4 r0 = *(const f32x4*)&src[(size_t)(c0 + 0) * TD + s0 + su];
            f32x4 r1 = *(const f32x4*)&src[(size_t)(c0 + 1) * TD + s0 + su];
            f32x4 r2 = *(const f32x4*)&src[(size_t)(c0 + 2) * TD + s0 + su];
            f32x4 r3 = *(const f32x4*)&src[(size_t)(c0 + 3) * TD + s0 + su];
            #pragma unroll
            for (int s = 0; s < 4; ++s) {
                short4 w;
                w.x = f2bf(r0[s]); w.y = f2bf(r1[s]);
                w.z = f2bf(r2[s]); w.w = f2bf(r3[s]);
                *(short4*)&Tl[su + s][c0] = w;
            }
        }
        __syncthreads();
        char* kt0 = ws + ((size_t)b * NKV + 2 * sb) * TILE_B;
        #pragma unroll
        for (int it = 0; it < 4; ++it) {
            int row = (tid >> 4) + 16 * it;     // 0..63 source s
            int p   = tid & 15;                 // cblk
            *(f32x4*)(kt0 + (row >> 5) * TILE_B + p * 512 + (row & 31) * 16)
                = *(const f32x4*)&Tl[row][p * 8];
        }
    } else {
        // V: tile[sblk][c][8 s-values], contiguous 16B stores per (c, chunk)
        char* vt0 = ws + VBASE + ((size_t)b * NKV + 2 * sb) * TILE_B;
        int c  = tid >> 1;
        int hh = tid & 1;
        #pragma unroll
        for (int i = 0; i < 4; ++i) {
            int q = 4 * hh + i;                 // 8B-pair chunk 0..7 over 64 s
            f32x4 a0 = *(const f32x4*)&src[(size_t)c * TD + s0 + q * 8];
            f32x4 a1 = *(const f32x4*)&src[(size_t)c * TD + s0 + q * 8 + 4];
            bf16x8 w;
            w[0] = f2bf(a0[0]); w[1] = f2bf(a0[1]); w[2] = f2bf(a0[2]); w[3] = f2bf(a0[3]);
            w[4] = f2bf(a1[0]); w[5] = f2bf(a1[1]); w[6] = f2bf(a1[2]); w[7] = f2bf(a1[3]);
            *(bf16x8*)(vt0 + (q >> 2) * TILE_B + (q & 3) * 2048 + c * 16) = w;
        }
    }
}

// ---------------------------------------------------------------------------
// Attention: dual 32-col tiles per wave, VALU diet, NO setprio (lockstep
// structure: m190 precedent), vf reads hoisted to overlap softmax latency.
// ---------------------------------------------------------------------------
__global__ __launch_bounds__(256, 2)
void attn_fwd(const float* __restrict__ qkv, const char* __restrict__ ws,
              float* __restrict__ out)
{
    // XCD-bijective decode (256t blocks: i&7 round-robin is HW-verified)
    int i    = blockIdx.x;            // 512 workgroups
    int xcd  = i & 7;
    int slot = i >> 3;                // 0..63
    int b    = xcd * 8 + (slot >> 3);
    int tt   = slot & 7;
    int t0   = tt * QBLK;

    int tid  = threadIdx.x;
    int wid  = tid >> 6;              // wave 0..3: rows [t0+64*wid, +64)
    int lane = tid & 63;
    int h    = lane >> 5;             // k-half
    int tcol = lane & 31;

    const char*  ktb = ws + (size_t)b * NKV * TILE_B;
    const char*  vtb = ws + VBASE + (size_t)b * NKV * TILE_B;
    const float* qb  = qkv + (size_t)b * 3 * CD * TD;

    __shared__ short Klds[2][KVB * CD];  // 2 x 8KB plane-major
    __shared__ short Vlds[2][CD * KVB];  // 2 x 8KB plane-major
    char* k0 = (char*)&Klds[0][0];
    char* k1 = (char*)&Klds[1][0];
    char* v0 = (char*)&Vlds[0][0];
    char* v1 = (char*)&Vlds[1][0];

    int wb = wid * 1024;              // per-wave 64 lanes x 16B
    int lo = lane * 16;
    int kbase = h * 512  + tcol * 16; // K read: + kt*1024
    int vbase = h * 2048 + tcol * 16; // V read: + kt2*4096 + mt*512

    // ---- Q fragments fp32->bf16, scale*log2e folded. Two column tiles. ----
    const float SCALE2 = 0.12751743f;   // log2(e)/sqrt(128)
    int tq = t0 + 64 * wid + tcol;      // ntile0 col; ntile1 col = tq+32
    bf16x8 qf0[8], qf1[8];
    #pragma unroll
    for (int kt = 0; kt < 8; ++kt)
        #pragma unroll
        for (int j = 0; j < 8; ++j) {
            size_t row = (size_t)(16 * kt + 8 * h + j) * TD;
            qf0[kt][j] = f2bf(qb[row + tq] * SCALE2);
            qf1[kt][j] = f2bf(qb[row + tq + 32] * SCALE2);
        }
    __builtin_amdgcn_sched_barrier(0);

    // ---- prologue: stage tile 0 into buffer 0 (K then V) ----
    #pragma unroll
    for (int it = 0; it < 2; ++it)
        gl_lds16(ktb + it * 4096 + wb + lo, k0 + it * 4096 + wb);
    #pragma unroll
    for (int it = 0; it < 2; ++it)
        gl_lds16(vtb + it * 4096 + wb + lo, v0 + it * 4096 + wb);

    f32x16 o0[4], o1[4];
    #pragma unroll
    for (int mt = 0; mt < 4; ++mt) { o0[mt] = (f32x16)(0.0f); o1[mt] = (f32x16)(0.0f); }
    float m0 = -1e30f, lsum0 = 0.0f;
    float m1 = -1e30f, lsum1 = 0.0f;

    auto ITER = [&](int sb, char* kc, char* vc, char* kn, char* vn)
        __attribute__((always_inline))
    {
        int nxt = (sb + 1 < NKV) ? (sb + 1) : sb;   // clamped: uniform pipeline

        // ---- tile sb resident; all waves done reading the other buffer ----
        asm volatile("s_waitcnt vmcnt(0)" ::: "memory");
        __builtin_amdgcn_sched_barrier(0);
        __builtin_amdgcn_s_barrier();
        __builtin_amdgcn_sched_barrier(0);

        // ---- prefetch tile sb+1 into the other buffer ----
        {
            const char* kg = ktb + (size_t)nxt * TILE_B;
            const char* vg = vtb + (size_t)nxt * TILE_B;
            #pragma unroll
            for (int it = 0; it < 2; ++it)
                gl_lds16(kg + it * 4096 + wb + lo, kn + it * 4096 + wb);
            #pragma unroll
            for (int it = 0; it < 2; ++it)
                gl_lds16(vg + it * 4096 + wb + lo, vn + it * 4096 + wb);
        }

        // ---- QK^T swapped, dual n-tile: each kf feeds two MFMAs ----
        f32x16 acc0 = (f32x16)(0.0f), acc1 = (f32x16)(0.0f);
        #pragma unroll
        for (int kt = 0; kt < 8; ++kt) {
            bf16x8 kf = *(const bf16x8*)(kc + kbase + kt * 1024);
            acc0 = __builtin_amdgcn_mfma_f32_32x32x16_bf16(kf, qf0[kt], acc0, 0, 0, 0);
            acc1 = __builtin_amdgcn_mfma_f32_32x32x16_bf16(kf, qf1[kt], acc1, 0, 0, 0);
        }

        // ---- hoist V reads: LDS latency overlaps the whole softmax phase ----
        bf16x8 vf[8];
        #pragma unroll
        for (int f = 0; f < 8; ++f)
            vf[f] = *(const bf16x8*)(vc + vbase + (f >> 2) * 4096 + (f & 3) * 512);

        // ---- softmax (exp2 domain), VALU diet: max3 trees + raw v_exp ----
        float pm0, pm1;
        {
            float t1 = mx3(acc0[0],  acc0[1],  acc0[2]);
            float t2 = mx3(acc0[3],  acc0[4],  acc0[5]);
            float t3 = mx3(acc0[6],  acc0[7],  acc0[8]);
            float t4 = mx3(acc0[9],  acc0[10], acc0[11]);
            float t5 = mx3(acc0[12], acc0[13], acc0[14]);
            pm0 = fmaxf(mx3(t1, t2, t3), mx3(t4, t5, acc0[15]));
        }
        {
            float t1 = mx3(acc1[0],  acc1[1],  acc1[2]);
            float t2 = mx3(acc1[3],  acc1[4],  acc1[5]);
            float t3 = mx3(acc1[6],  acc1[7],  acc1[8]);
            float t4 = mx3(acc1[9],  acc1[10], acc1[11]);
            float t5 = mx3(acc1[12], acc1[13], acc1[14]);
            pm1 = fmaxf(mx3(t1, t2, t3), mx3(t4, t5, acc1[15]));
        }

        int okk = (pm0 <= m0 + 8.0f) && (pm1 <= m1 + 8.0f);
        if (!__all(okk)) {
            float rm0 = fmaxf(m0, fmaxf(pm0, __shfl_xor(pm0, 32, 64)));
            float rm1 = fmaxf(m1, fmaxf(pm1, __shfl_xor(pm1, 32, 64)));
            float cr0 = ex2(m0 - rm0);
            float cr1 = ex2(m1 - rm1);
            m0 = rm0; m1 = rm1;
            lsum0 *= cr0; lsum1 *= cr1;
            #pragma unroll
            for (int mt = 0; mt < 4; ++mt)
                #pragma unroll
                for (int r = 0; r < 16; ++r) {
                    o0[mt][r] *= cr0;
                    o1[mt][r] *= cr1;
                }
        }
        {
            float s0a = 0.f, s1a = 0.f, s2a = 0.f, s3a = 0.f;
            #pragma unroll
            for (int r = 0; r < 16; r += 4) {
                acc0[r + 0] = ex2(acc0[r + 0] - m0);
                acc0[r + 1] = ex2(acc0[r + 1] - m0);
                acc0[r + 2] = ex2(acc0[r + 2] - m0);
                acc0[r + 3] = ex2(acc0[r + 3] - m0);
                s0a += acc0[r + 0]; s1a += acc0[r + 1];
                s2a += acc0[r + 2]; s3a += acc0[r + 3];
            }
            lsum0 += (s0a + s1a) + (s2a + s3a);
        }
        {
            float s0a = 0.f, s1a = 0.f, s2a = 0.f, s3a = 0.f;
            #pragma unroll
            for (int r = 0; r < 16; r += 4) {
                acc1[r + 0] = ex2(acc1[r + 0] - m1);
                acc1[r + 1] = ex2(acc1[r + 1] - m1);
                acc1[r + 2] = ex2(acc1[r + 2] - m1);
                acc1[r + 3] = ex2(acc1[r + 3] - m1);
                s0a += acc1[r + 0]; s1a += acc1[r + 1];
                s2a += acc1[r + 2]; s3a += acc1[r + 3];
            }
            lsum1 += (s0a + s1a) + (s2a + s3a);
        }

        // ---- P^T -> PV B-frags in-register: cvt_pk + lane^32 exchange ----
        unsigned p0[2][4], p1[2][4];
        #pragma unroll
        for (int e = 0; e < 2; ++e) {
            unsigned k0_, k1_, k2_, k3_;
            asm("v_cvt_pk_bf16_f32 %0, %1, %2" : "=v"(k0_) : "v"(acc0[8*e+0]), "v"(acc0[8*e+1]));
            asm("v_cvt_pk_bf16_f32 %0, %1, %2" : "=v"(k1_) : "v"(acc0[8*e+2]), "v"(acc0[8*e+3]));
            asm("v_cvt_pk_bf16_f32 %0, %1, %2" : "=v"(k2_) : "v"(acc0[8*e+4]), "v"(acc0[8*e+5]));
            asm("v_cvt_pk_bf16_f32 %0, %1, %2" : "=v"(k3_) : "v"(acc0[8*e+6]), "v"(acc0[8*e+7]));
            unsigned sA = h ? k0_ : k2_;
            unsigned sB = h ? k1_ : k3_;
            unsigned r0 = (unsigned)__shfl_xor((int)sA, 32, 64);
            unsigned r1 = (unsigned)__shfl_xor((int)sB, 32, 64);
            p0[e][0] = h ? r0 : k0_;
            p0[e][1] = h ? r1 : k1_;
            p0[e][2] = h ? k2_ : r0;
            p0[e][3] = h ? k3_ : r1;
        }
        #pragma unroll
        for (int e = 0; e < 2; ++e) {
            unsigned k0_, k1_, k2_, k3_;
            asm("v_cvt_pk_bf16_f32 %0, %1, %2" : "=v"(k0_) : "v"(acc1[8*e+0]), "v"(acc1[8*e+1]));
            asm("v_cvt_pk_bf16_f32 %0, %1, %2" : "=v"(k1_) : "v"(acc1[8*e+2]), "v"(acc1[8*e+3]));
            asm("v_cvt_pk_bf16_f32 %0, %1, %2" : "=v"(k2_) : "v"(acc1[8*e+4]), "v"(acc1[8*e+5]));
            asm("v_cvt_pk_bf16_f32 %0, %1, %2" : "=v"(k3_) : "v"(acc1[8*e+6]), "v"(acc1[8*e+7]));
            unsigned sA = h ? k0_ : k2_;
            unsigned sB = h ? k1_ : k3_;
            unsigned r0 = (unsigned)__shfl_xor((int)sA, 32, 64);
            unsigned r1 = (unsigned)__shfl_xor((int)sB, 32, 64);
            p1[e][0] = h ? r0 : k0_;
            p1[e][1] = h ? r1 : k1_;
            p1[e][2] = h ? k2_ : r0;
            p1[e][3] = h ? k3_ : r1;
        }

        // ---- PV swapped, dual n-tile: each vf feeds two MFMAs ----
        #pragma unroll
        for (int kt2 = 0; kt2 < 2; ++kt2) {
            union { unsigned u[4]; bf16x8 v; } w0, w1;
            w0.u[0] = p0[kt2][0]; w0.u[1] = p0[kt2][1];
            w0.u[2] = p0[kt2][2]; w0.u[3] = p0[kt2][3];
            w1.u[0] = p1[kt2][0]; w1.u[1] = p1[kt2][1];
            w1.u[2] = p1[kt2][2]; w1.u[3] = p1[kt2][3];
            #pragma unroll
            for (int mt = 0; mt < 4; ++mt) {
                o0[mt] = __builtin_amdgcn_mfma_f32_32x32x16_bf16(vf[kt2 * 4 + mt], w0.v, o0[mt], 0, 0, 0);
                o1[mt] = __builtin_amdgcn_mfma_f32_32x32x16_bf16(vf[kt2 * 4 + mt], w1.v, o1[mt], 0, 0, 0);
            }
        }
    };

    #pragma unroll 1
    for (int s2 = 0; s2 < NKV; s2 += 2) {
        ITER(s2,     k0, v0, k1, v1);
        ITER(s2 + 1, k1, v1, k0, v0);
    }

    // drain redundant tail prefetch before exit
    asm volatile("s_waitcnt vmcnt(0)" ::: "memory");
    __builtin_amdgcn_sched_barrier(0);

    // ---- epilogue: finish denominators across lane^32 pair, store ----
    lsum0 += __shfl_xor(lsum0, 32, 64);
    lsum1 += __shfl_xor(lsum1, 32, 64);
    float inv0 = 1.0f / lsum0;
    float inv1 = 1.0f / lsum1;
    float* ob = out + (size_t)b * CD * TD;
    #pragma unroll
    for (int mt = 0; mt < 4; ++mt)
        #pragma unroll
        for (int r = 0; r < 16; ++r) {
            int c = 32 * mt + (r & 3) + 8 * (r >> 2) + 4 * h;
            ob[(size_t)c * TD + tq]      = o0[mt][r] * inv0;
            ob[(size_t)c * TD + tq + 32] = o1[mt][r] * inv1;
        }
}

extern "C" void kernel_launch(void* const* d_in, const int* in_sizes, int n_in,
                              void* d_out, int out_size, void* d_ws, size_t ws_size,
                              hipStream_t stream)
{
    const float* qkv = (const float*)d_in[0];
    float* out = (float*)d_out;
    char* ws = (char*)d_ws;
    prepass<<<dim3(NB * 64), 256, 0, stream>>>(qkv, ws);                   // 4096 wgs
    attn_fwd<<<dim3(NB * NQT), 256, 0, stream>>>(qkv, ws, out);            // 512 wgs
}

// Round 17
// 195.117 us; speedup vs baseline: 1.1790x; 1.1790x over previous
//
#include <hip/hip_runtime.h>
#include <math.h>

typedef __attribute__((ext_vector_type(4)))  float f32x4;
typedef __attribute__((ext_vector_type(16))) float f32x16;
typedef __attribute__((ext_vector_type(8)))  short bf16x8;

#define NB   64
#define CD   128
#define TD   2048
#define QBLK 256             // per block (4 waves x 64 rows, dual 32-col tiles)
#define KVB  32
#define NKV  (TD / KVB)      // 64
#define NQT  (TD / QBLK)     // 8

#define TILE_B   8192        // K tile: [cblk 0..15][s 0..31] 16B ; V tile: [sblk 0..3][c 0..127] 16B
#define VBASE    ((size_t)NB * NKV * TILE_B)   // 33,554,432 (total ws = 64 MB)

__device__ __forceinline__ short f2bf(float f) {
    union { float f; unsigned u; } x; x.f = f;
    unsigned r = x.u + 0x7FFFu + ((x.u >> 16) & 1u);   // RNE
    return (short)(r >> 16);
}

__device__ __forceinline__ float ex2(float x) {      // raw v_exp_f32 (1 instr)
    return __builtin_amdgcn_exp2f(x);
}
__device__ __forceinline__ float mx3(float a, float b, float c) {
    return fmaxf(fmaxf(a, b), c);                    // fuses to v_max3_f32
}

__device__ __forceinline__ void gl_lds16(const void* g, void* l) {
    __builtin_amdgcn_global_load_lds(
        (__attribute__((address_space(1))) void*)g,
        (__attribute__((address_space(3))) void*)l, 16, 0, 0);
}

// ---------------------------------------------------------------------------
// Prepass: K -> plane-major transposed tiles [cblk][s][8c], V -> plane-major
// natural tiles [sblk][c][8s]. MFMA b128 reads then need no XOR swizzle.
// ---------------------------------------------------------------------------
__global__ __launch_bounds__(256)
void prepass(const float* __restrict__ qkv, char* __restrict__ ws)
{
    int blk  = blockIdx.x;            // 64 b * 64 (kind,sb)
    int b    = blk >> 6;
    int rem  = blk & 63;
    int kind = rem >> 5;              // 0=K, 1=V
    int sb   = rem & 31;              // 64-row source slab -> 2 tiles
    int s0   = sb * 64;
    int tid  = threadIdx.x;
    const float* src = qkv + ((size_t)b * 3 + 1 + kind) * CD * TD;

    if (kind == 0) {
        // K transpose: stage [s'][c] in LDS, emit plane-major tiles
        __shared__ short Tl[64][CD + 8];
        int su = (tid & 15) * 4;
        int cb = 4 * (tid >> 4);
        #pragma unroll
        for (int it = 0; it < 2; ++it) {
            int c0 = cb + 64 * it;
            f32x4 r0 = *(const f32x4*)&src[(size_t)(c0 + 0) * TD + s0 + su];
            f32x4 r1 = *(const f32x4*)&src[(size_t)(c0 + 1) * TD + s0 + su];
            f32x4 r2 = *(const f32x4*)&src[(size_t)(c0 + 2) * TD + s0 + su];
            f32x4 r3 = *(const f32x4*)&src[(size_t)(c0 + 3) * TD + s0 + su];
            #pragma unroll
            for (int s = 0; s < 4; ++s) {
                short4 w;
                w.x = f2bf(r0[s]); w.y = f2bf(r1[s]);
                w.z = f2bf(r2[s]); w.w = f2bf(r3[s]);
                *(short4*)&Tl[su + s][c0] = w;
            }
        }
        __syncthreads();
        char* kt0 = ws + ((size_t)b * NKV + 2 * sb) * TILE_B;
        #pragma unroll
        for (int it = 0; it < 4; ++it) {
            int row = (tid >> 4) + 16 * it;     // 0..63 source s
            int p   = tid & 15;                 // cblk
            *(f32x4*)(kt0 + (row >> 5) * TILE_B + p * 512 + (row & 31) * 16)
                = *(const f32x4*)&Tl[row][p * 8];
        }
    } else {
        // V: tile[sblk][c][8 s-values], contiguous 16B stores per (c, chunk)
        char* vt0 = ws + VBASE + ((size_t)b * NKV + 2 * sb) * TILE_B;
        int c  = tid >> 1;
        int hh = tid & 1;
        #pragma unroll
        for (int i = 0; i < 4; ++i) {
            int q = 4 * hh + i;                 // 8B-pair chunk 0..7 over 64 s
            f32x4 a0 = *(const f32x4*)&src[(size_t)c * TD + s0 + q * 8];
            f32x4 a1 = *(const f32x4*)&src[(size_t)c * TD + s0 + q * 8 + 4];
            bf16x8 w;
            w[0] = f2bf(a0[0]); w[1] = f2bf(a0[1]); w[2] = f2bf(a0[2]); w[3] = f2bf(a0[3]);
            w[4] = f2bf(a1[0]); w[5] = f2bf(a1[1]); w[6] = f2bf(a1[2]); w[7] = f2bf(a1[3]);
            *(bf16x8*)(vt0 + (q >> 2) * TILE_B + (q & 3) * 2048 + c * 16) = w;
        }
    }
}

// ---------------------------------------------------------------------------
// Attention: dual 32-col tiles per wave (shared K/V ds_reads halve LDS-pipe
// pressure), grid 512 = balanced 2 blocks/CU, VALU diet (v_exp_f32, v_max3).
// ---------------------------------------------------------------------------
__global__ __launch_bounds__(256, 2)
void attn_fwd(const float* __restrict__ qkv, const char* __restrict__ ws,
              float* __restrict__ out)
{
    // XCD-bijective decode (256t blocks: i&7 round-robin is HW-verified)
    int i    = blockIdx.x;            // 512 workgroups
    int xcd  = i & 7;
    int slot = i >> 3;                // 0..63
    int b    = xcd * 8 + (slot >> 3);
    int tt   = slot & 7;
    int t0   = tt * QBLK;

    int tid  = threadIdx.x;
    int wid  = tid >> 6;              // wave 0..3: rows [t0+64*wid, +64)
    int lane = tid & 63;
    int h    = lane >> 5;             // k-half
    int tcol = lane & 31;

    const char*  ktb = ws + (size_t)b * NKV * TILE_B;
    const char*  vtb = ws + VBASE + (size_t)b * NKV * TILE_B;
    const float* qb  = qkv + (size_t)b * 3 * CD * TD;

    __shared__ short Klds[2][KVB * CD];  // 2 x 8KB plane-major
    __shared__ short Vlds[2][CD * KVB];  // 2 x 8KB plane-major
    char* k0 = (char*)&Klds[0][0];
    char* k1 = (char*)&Klds[1][0];
    char* v0 = (char*)&Vlds[0][0];
    char* v1 = (char*)&Vlds[1][0];

    int wb = wid * 1024;              // per-wave 64 lanes x 16B
    int lo = lane * 16;
    int kbase = h * 512  + tcol * 16; // K read: + kt*1024
    int vbase = h * 2048 + tcol * 16; // V read: + kt2*4096 + mt*512

    // ---- Q fragments fp32->bf16, scale*log2e folded. Two column tiles. ----
    const float SCALE2 = 0.12751743f;   // log2(e)/sqrt(128)
    int tq = t0 + 64 * wid + tcol;      // ntile0 col; ntile1 col = tq+32
    bf16x8 qf0[8], qf1[8];
    #pragma unroll
    for (int kt = 0; kt < 8; ++kt)
        #pragma unroll
        for (int j = 0; j < 8; ++j) {
            size_t row = (size_t)(16 * kt + 8 * h + j) * TD;
            qf0[kt][j] = f2bf(qb[row + tq] * SCALE2);
            qf1[kt][j] = f2bf(qb[row + tq + 32] * SCALE2);
        }
    __builtin_amdgcn_sched_barrier(0);

    // ---- prologue: stage tile 0 into buffer 0 (K then V) ----
    #pragma unroll
    for (int it = 0; it < 2; ++it)
        gl_lds16(ktb + it * 4096 + wb + lo, k0 + it * 4096 + wb);
    #pragma unroll
    for (int it = 0; it < 2; ++it)
        gl_lds16(vtb + it * 4096 + wb + lo, v0 + it * 4096 + wb);

    f32x16 o0[4], o1[4];
    #pragma unroll
    for (int mt = 0; mt < 4; ++mt) { o0[mt] = (f32x16)(0.0f); o1[mt] = (f32x16)(0.0f); }
    float m0 = -1e30f, lsum0 = 0.0f;
    float m1 = -1e30f, lsum1 = 0.0f;

    auto ITER = [&](int sb, char* kc, char* vc, char* kn, char* vn)
        __attribute__((always_inline))
    {
        int nxt = (sb + 1 < NKV) ? (sb + 1) : sb;   // clamped: uniform pipeline

        // ---- tile sb resident; all waves done reading the other buffer ----
        asm volatile("s_waitcnt vmcnt(0)" ::: "memory");
        __builtin_amdgcn_sched_barrier(0);
        __builtin_amdgcn_s_barrier();
        __builtin_amdgcn_sched_barrier(0);

        // ---- prefetch tile sb+1 into the other buffer ----
        {
            const char* kg = ktb + (size_t)nxt * TILE_B;
            const char* vg = vtb + (size_t)nxt * TILE_B;
            #pragma unroll
            for (int it = 0; it < 2; ++it)
                gl_lds16(kg + it * 4096 + wb + lo, kn + it * 4096 + wb);
            #pragma unroll
            for (int it = 0; it < 2; ++it)
                gl_lds16(vg + it * 4096 + wb + lo, vn + it * 4096 + wb);
        }

        // ---- QK^T swapped, dual n-tile: each kf feeds two MFMAs ----
        f32x16 acc0 = (f32x16)(0.0f), acc1 = (f32x16)(0.0f);
        __builtin_amdgcn_s_setprio(1);
        #pragma unroll
        for (int kt = 0; kt < 8; ++kt) {
            bf16x8 kf = *(const bf16x8*)(kc + kbase + kt * 1024);
            acc0 = __builtin_amdgcn_mfma_f32_32x32x16_bf16(kf, qf0[kt], acc0, 0, 0, 0);
            acc1 = __builtin_amdgcn_mfma_f32_32x32x16_bf16(kf, qf1[kt], acc1, 0, 0, 0);
        }
        __builtin_amdgcn_s_setprio(0);

        // ---- softmax (exp2 domain), VALU diet: max3 trees + raw v_exp ----
        float pm0, pm1;
        {
            float t1 = mx3(acc0[0],  acc0[1],  acc0[2]);
            float t2 = mx3(acc0[3],  acc0[4],  acc0[5]);
            float t3 = mx3(acc0[6],  acc0[7],  acc0[8]);
            float t4 = mx3(acc0[9],  acc0[10], acc0[11]);
            float t5 = mx3(acc0[12], acc0[13], acc0[14]);
            pm0 = fmaxf(mx3(t1, t2, t3), mx3(t4, t5, acc0[15]));
        }
        {
            float t1 = mx3(acc1[0],  acc1[1],  acc1[2]);
            float t2 = mx3(acc1[3],  acc1[4],  acc1[5]);
            float t3 = mx3(acc1[6],  acc1[7],  acc1[8]);
            float t4 = mx3(acc1[9],  acc1[10], acc1[11]);
            float t5 = mx3(acc1[12], acc1[13], acc1[14]);
            pm1 = fmaxf(mx3(t1, t2, t3), mx3(t4, t5, acc1[15]));
        }

        int okk = (pm0 <= m0 + 8.0f) && (pm1 <= m1 + 8.0f);
        if (!__all(okk)) {
            float rm0 = fmaxf(m0, fmaxf(pm0, __shfl_xor(pm0, 32, 64)));
            float rm1 = fmaxf(m1, fmaxf(pm1, __shfl_xor(pm1, 32, 64)));
            float cr0 = ex2(m0 - rm0);
            float cr1 = ex2(m1 - rm1);
            m0 = rm0; m1 = rm1;
            lsum0 *= cr0; lsum1 *= cr1;
            #pragma unroll
            for (int mt = 0; mt < 4; ++mt)
                #pragma unroll
                for (int r = 0; r < 16; ++r) {
                    o0[mt][r] *= cr0;
                    o1[mt][r] *= cr1;
                }
        }
        {
            float s0a = 0.f, s1a = 0.f, s2a = 0.f, s3a = 0.f;
            #pragma unroll
            for (int r = 0; r < 16; r += 4) {
                acc0[r + 0] = ex2(acc0[r + 0] - m0);
                acc0[r + 1] = ex2(acc0[r + 1] - m0);
                acc0[r + 2] = ex2(acc0[r + 2] - m0);
                acc0[r + 3] = ex2(acc0[r + 3] - m0);
                s0a += acc0[r + 0]; s1a += acc0[r + 1];
                s2a += acc0[r + 2]; s3a += acc0[r + 3];
            }
            lsum0 += (s0a + s1a) + (s2a + s3a);
        }
        {
            float s0a = 0.f, s1a = 0.f, s2a = 0.f, s3a = 0.f;
            #pragma unroll
            for (int r = 0; r < 16; r += 4) {
                acc1[r + 0] = ex2(acc1[r + 0] - m1);
                acc1[r + 1] = ex2(acc1[r + 1] - m1);
                acc1[r + 2] = ex2(acc1[r + 2] - m1);
                acc1[r + 3] = ex2(acc1[r + 3] - m1);
                s0a += acc1[r + 0]; s1a += acc1[r + 1];
                s2a += acc1[r + 2]; s3a += acc1[r + 3];
            }
            lsum1 += (s0a + s1a) + (s2a + s3a);
        }

        // ---- P^T -> PV B-frags in-register: cvt_pk + lane^32 exchange ----
        unsigned p0[2][4], p1[2][4];
        #pragma unroll
        for (int e = 0; e < 2; ++e) {
            unsigned k0_, k1_, k2_, k3_;
            asm("v_cvt_pk_bf16_f32 %0, %1, %2" : "=v"(k0_) : "v"(acc0[8*e+0]), "v"(acc0[8*e+1]));
            asm("v_cvt_pk_bf16_f32 %0, %1, %2" : "=v"(k1_) : "v"(acc0[8*e+2]), "v"(acc0[8*e+3]));
            asm("v_cvt_pk_bf16_f32 %0, %1, %2" : "=v"(k2_) : "v"(acc0[8*e+4]), "v"(acc0[8*e+5]));
            asm("v_cvt_pk_bf16_f32 %0, %1, %2" : "=v"(k3_) : "v"(acc0[8*e+6]), "v"(acc0[8*e+7]));
            unsigned sA = h ? k0_ : k2_;
            unsigned sB = h ? k1_ : k3_;
            unsigned r0 = (unsigned)__shfl_xor((int)sA, 32, 64);
            unsigned r1 = (unsigned)__shfl_xor((int)sB, 32, 64);
            p0[e][0] = h ? r0 : k0_;
            p0[e][1] = h ? r1 : k1_;
            p0[e][2] = h ? k2_ : r0;
            p0[e][3] = h ? k3_ : r1;
        }
        #pragma unroll
        for (int e = 0; e < 2; ++e) {
            unsigned k0_, k1_, k2_, k3_;
            asm("v_cvt_pk_bf16_f32 %0, %1, %2" : "=v"(k0_) : "v"(acc1[8*e+0]), "v"(acc1[8*e+1]));
            asm("v_cvt_pk_bf16_f32 %0, %1, %2" : "=v"(k1_) : "v"(acc1[8*e+2]), "v"(acc1[8*e+3]));
            asm("v_cvt_pk_bf16_f32 %0, %1, %2" : "=v"(k2_) : "v"(acc1[8*e+4]), "v"(acc1[8*e+5]));
            asm("v_cvt_pk_bf16_f32 %0, %1, %2" : "=v"(k3_) : "v"(acc1[8*e+6]), "v"(acc1[8*e+7]));
            unsigned sA = h ? k0_ : k2_;
            unsigned sB = h ? k1_ : k3_;
            unsigned r0 = (unsigned)__shfl_xor((int)sA, 32, 64);
            unsigned r1 = (unsigned)__shfl_xor((int)sB, 32, 64);
            p1[e][0] = h ? r0 : k0_;
            p1[e][1] = h ? r1 : k1_;
            p1[e][2] = h ? k2_ : r0;
            p1[e][3] = h ? k3_ : r1;
        }

        // ---- PV swapped, dual n-tile: each vf feeds two MFMAs ----
        __builtin_amdgcn_s_setprio(1);
        #pragma unroll
        for (int kt2 = 0; kt2 < 2; ++kt2) {
            union { unsigned u[4]; bf16x8 v; } w0, w1;
            w0.u[0] = p0[kt2][0]; w0.u[1] = p0[kt2][1];
            w0.u[2] = p0[kt2][2]; w0.u[3] = p0[kt2][3];
            w1.u[0] = p1[kt2][0]; w1.u[1] = p1[kt2][1];
            w1.u[2] = p1[kt2][2]; w1.u[3] = p1[kt2][3];
            #pragma unroll
            for (int mt = 0; mt < 4; ++mt) {
                bf16x8 vf = *(const bf16x8*)(vc + vbase + kt2 * 4096 + mt * 512);
                o0[mt] = __builtin_amdgcn_mfma_f32_32x32x16_bf16(vf, w0.v, o0[mt], 0, 0, 0);
                o1[mt] = __builtin_amdgcn_mfma_f32_32x32x16_bf16(vf, w1.v, o1[mt], 0, 0, 0);
            }
        }
        __builtin_amdgcn_s_setprio(0);
    };

    #pragma unroll 1
    for (int s2 = 0; s2 < NKV; s2 += 2) {
        ITER(s2,     k0, v0, k1, v1);
        ITER(s2 + 1, k1, v1, k0, v0);
    }

    // drain redundant tail prefetch before exit
    asm volatile("s_waitcnt vmcnt(0)" ::: "memory");
    __builtin_amdgcn_sched_barrier(0);

    // ---- epilogue: finish denominators across lane^32 pair, store ----
    lsum0 += __shfl_xor(lsum0, 32, 64);
    lsum1 += __shfl_xor(lsum1, 32, 64);
    float inv0 = 1.0f / lsum0;
    float inv1 = 1.0f / lsum1;
    float* ob = out + (size_t)b * CD * TD;
    #pragma unroll
    for (int mt = 0; mt < 4; ++mt)
        #pragma unroll
        for (int r = 0; r < 16; ++r) {
            int c = 32 * mt + (r & 3) + 8 * (r >> 2) + 4 * h;
            ob[(size_t)c * TD + tq]      = o0[mt][r] * inv0;
            ob[(size_t)c * TD + tq + 32] = o1[mt][r] * inv1;
        }
}

extern "C" void kernel_launch(void* const* d_in, const int* in_sizes, int n_in,
                              void* d_out, int out_size, void* d_ws, size_t ws_size,
                              hipStream_t stream)
{
    const float* qkv = (const float*)d_in[0];
    float* out = (float*)d_out;
    char* ws = (char*)d_ws;
    prepass<<<dim3(NB * 64), 256, 0, stream>>>(qkv, ws);                   // 4096 wgs
    attn_fwd<<<dim3(NB * NQT), 256, 0, stream>>>(qkv, ws, out);            // 512 wgs
}